// Round 3
// baseline (85.510 us; speedup 1.0000x reference)
//
#include <hip/hip_runtime.h>
#include <math.h>

// Problem constants (from reference): N=4, C=128, H=W=256, G=4, K=5, DIL=1
#define NB   4
#define CC   128
#define HH   256
#define WW   256
#define HWSZ (HH * WW)          // 65536
#define NC   (NB * CC)          // 512
#define GK   20                 // G*K

__device__ __forceinline__ float wave_reduce_sum(float v) {
#pragma unroll
    for (int o = 1; o < 64; o <<= 1) v += __shfl_xor(v, o, 64);
    return v;
}

// ---------------------------------------------------------------------------
// Kernel 1: partial plane reductions. 4 blocks per (n,c) plane, 64 rows each.
// Produces: rowsum[b][h] (exclusive rows, no atomics), partial colsum
// [b][chunk][w], partial planesum [b*4+chunk]. Deterministic.
// ---------------------------------------------------------------------------
__global__ __launch_bounds__(256) void k_reduce(const float4* __restrict__ x4,
                                                float* __restrict__ rowsum,
                                                float* __restrict__ colsum_part,
                                                float* __restrict__ planesum_part) {
    const int bx = blockIdx.x;
    const int b = bx >> 2;               // (n,c) index
    const int chunk = bx & 3;            // row chunk 0..3
    const int t = threadIdx.x;
    const int wv = t >> 6;               // wave id 0..3
    const int l = t & 63;                // lane
    const float4* plane = x4 + (size_t)b * (HWSZ / 4);
    const int r0 = chunk * 64 + wv * 16; // this wave's 16 rows

    float4 cs = make_float4(0.f, 0.f, 0.f, 0.f);
#pragma unroll 4
    for (int i = 0; i < 16; ++i) {
        float4 v = plane[(r0 + i) * (WW / 4) + l];
        cs.x += v.x; cs.y += v.y; cs.z += v.z; cs.w += v.w;
        float rs = wave_reduce_sum((v.x + v.y) + (v.z + v.w));
        if (l == 0) rowsum[b * HH + r0 + i] = rs;
    }

    __shared__ float colpart[4][WW];
    colpart[wv][4 * l + 0] = cs.x;
    colpart[wv][4 * l + 1] = cs.y;
    colpart[wv][4 * l + 2] = cs.z;
    colpart[wv][4 * l + 3] = cs.w;
    __syncthreads();
    float c = (colpart[0][t] + colpart[1][t]) + (colpart[2][t] + colpart[3][t]);
    colsum_part[(size_t)b * 4 * WW + chunk * WW + t] = c;

    float p = wave_reduce_sum(c);
    __shared__ float pr[4];
    if (l == 0) pr[wv] = p;
    __syncthreads();
    if (t == 0) planesum_part[b * 4 + chunk] = (pr[0] + pr[1]) + (pr[2] + pr[3]);
}

// ---------------------------------------------------------------------------
// Kernel 2: tiny. Sums partials -> planesum; f_h = tanh(conv_h @ mean_x);
// analytic mean(out1); f_v = tanh(conv_v @ mean_out1). Single block.
// Reflect-pad boundary corrections for the horizontal conv plane-mean:
//   k=0 (shift -2): S + c1 + c2 - c254 - c255
//   k=1 (shift -1): S + c1 - c255
//   k=2 (shift  0): S
//   k=3 (shift +1): S + c254 - c0
//   k=4 (shift +2): S + c253 + c254 - c0 - c1
// ---------------------------------------------------------------------------
__global__ __launch_bounds__(256) void k_small(const float* __restrict__ colsum_part,
                                               const float* __restrict__ planesum_part,
                                               const float* __restrict__ conv_h,
                                               const float* __restrict__ inside_h,
                                               const float* __restrict__ lamb_l_h,
                                               const float* __restrict__ lamb_h_h,
                                               const float* __restrict__ conv_v,
                                               float* __restrict__ planesum,
                                               float* __restrict__ f_h_out,
                                               float* __restrict__ f_v_out) {
    __shared__ float meanx[NC];
    __shared__ float psum[NC];
    __shared__ float fh[NB * GK];
    __shared__ float mo1[NC];
    const int t = threadIdx.x;

    for (int i = t; i < NC; i += 256) {
        float S = (planesum_part[i * 4 + 0] + planesum_part[i * 4 + 1]) +
                  (planesum_part[i * 4 + 2] + planesum_part[i * 4 + 3]);
        psum[i] = S;
        planesum[i] = S;
        meanx[i] = S * (1.f / HWSZ);
    }
    __syncthreads();

    if (t < NB * GK) {
        const int n = t / GK, o = t % GK;
        float acc = 0.f;
        for (int c = 0; c < CC; ++c) acc += meanx[n * CC + c] * conv_h[o * CC + c];
        float v = tanhf(acc);
        fh[t] = v;
        f_h_out[t] = v;
    }
    __syncthreads();

    for (int i = t; i < NC; i += 256) {
        const int n = i >> 7, c = i & (CC - 1), g = c >> 5;
        const float* f = &fh[n * GK + g * 5];
        const float S = psum[i];
        const float* col = colsum_part + (size_t)i * 4 * WW;
        auto csum = [&](int w) {
            return (col[0 * WW + w] + col[1 * WW + w]) +
                   (col[2 * WW + w] + col[3 * WW + w]);
        };
        const float c0 = csum(0), c1 = csum(1), c2 = csum(2);
        const float c253 = csum(253), c254 = csum(254), c255 = csum(255);
        const float s0 = S + c1 + c2 - c254 - c255;
        const float s1 = S + c1 - c255;
        const float s2 = S;
        const float s3 = S + c254 - c0;
        const float s4 = S + c253 + c254 - c0 - c1;
        const float convmean =
            (f[0] * s0 + f[1] * s1 + f[2] * s2 + f[3] * s3 + f[4] * s4) * (1.f / HWSZ);
        const float A = (inside_h[c] + 1.f) * lamb_l_h[c];
        const float B = inside_h[c] * lamb_l_h[c];
        const float Cq = lamb_h_h[c] + 1.f;
        mo1[i] = A * convmean + (Cq - B) * meanx[i];
    }
    __syncthreads();

    if (t < NB * GK) {
        const int n = t / GK, o = t % GK;
        float acc = 0.f;
        for (int c = 0; c < CC; ++c) acc += mo1[n * CC + c] * conv_v[o * CC + c];
        f_v_out[t] = tanhf(acc);
    }
}

// ---------------------------------------------------------------------------
// Kernel 3: fused main pass, fully float4-vectorized.
// Wave = one row (64 lanes x float4). Block = 4 rows per iteration.
// Horizontal 5-tap in registers via shuffles (reflect edges = own regs).
// Row mean read from rowsum (prefetched; no in-loop shuffle reduce).
// hconv rows -> 16-row LDS ring; vertical 5-tap reads 5x ds_read_b128.
// Output lags load by 1 iter so x-center stays in reg.
// ---------------------------------------------------------------------------
#define TH 64  // rows per block tile

__global__ __launch_bounds__(256) void k_main(const float* __restrict__ x,
                                              const float* __restrict__ rowsum,
                                              const float* __restrict__ colsum_part,
                                              const float* __restrict__ planesum,
                                              const float* __restrict__ f_h,
                                              const float* __restrict__ f_v,
                                              const float* __restrict__ inside_h,
                                              const float* __restrict__ lamb_l_h,
                                              const float* __restrict__ lamb_h_h,
                                              const float* __restrict__ inside_v,
                                              const float* __restrict__ lamb_l_v,
                                              const float* __restrict__ lamb_h_v,
                                              const float* __restrict__ gamma,
                                              const float* __restrict__ beta,
                                              float* __restrict__ out) {
    const int b = blockIdx.x >> 2;        // (n,c)
    const int tile = blockIdx.x & 3;
    const int h0 = tile * TH;
    const int n = b >> 7, c = b & (CC - 1), g = c >> 5;
    const int t = threadIdx.x;
    const int wv = t >> 6;                // wave id 0..3
    const int l = t & 63;                 // lane

    float fh[5], fv[5];
#pragma unroll
    for (int k = 0; k < 5; ++k) {
        fh[k] = f_h[n * GK + g * 5 + k];
        fv[k] = f_v[n * GK + g * 5 + k];
    }
    const float Ah = (inside_h[c] + 1.f) * lamb_l_h[c];
    const float Bh = inside_h[c] * lamb_l_h[c];
    const float Ch = lamb_h_h[c] + 1.f;
    const float Av = (inside_v[c] + 1.f) * lamb_l_v[c];
    const float Bv = inside_v[c] * lamb_l_v[c];
    const float Cv = lamb_h_v[c] + 1.f;
    const float gm = gamma[c], bt = beta[c];
    const float meanx = planesum[b] * (1.f / HWSZ);

    // --- gapx_v per column (reflect-padded 5-tap over column means) ---
    __shared__ float lcol[WW + 4];
    {
        const float* col = colsum_part + (size_t)b * 4 * WW;
        float cm = ((col[0 * WW + t] + col[1 * WW + t]) +
                    (col[2 * WW + t] + col[3 * WW + t])) * (1.f / HH);
        lcol[t + 2] = cm;
        if (t < 2) {
            int w = 2 - t;
            lcol[t] = ((col[0 * WW + w] + col[1 * WW + w]) +
                       (col[2 * WW + w] + col[3 * WW + w])) * (1.f / HH);
        }
        if (t >= WW - 2) {
            int w = 2 * WW - 4 - t;
            lcol[t + 4] = ((col[0 * WW + w] + col[1 * WW + w]) +
                           (col[2 * WW + w] + col[3 * WW + w])) * (1.f / HH);
        }
    }
    __syncthreads();
    float gx[4];
    {
        float q[8];
#pragma unroll
        for (int d = 0; d < 8; ++d) q[d] = lcol[4 * l + d];
#pragma unroll
        for (int d = 0; d < 4; ++d) {
            gx[d] = Ah * (fh[0] * q[d] + fh[1] * q[d + 1] + fh[2] * q[d + 2] +
                          fh[3] * q[d + 3] + fh[4] * q[d + 4]) -
                    Bh * meanx + Ch * q[d + 2];
        }
    }

    __shared__ float hring[16][WW];       // hconv ring (16 rows)
    const float* plane = x + (size_t)b * HWSZ;
    float* oplane = out + (size_t)b * HWSZ;

    // reflected source row for super-iter j (wave wv)
    auto hrOf = [&](int j) -> int {
        int hs = h0 - 4 + 4 * j + wv;
        return hs < 0 ? -hs : (hs > HH - 1 ? 2 * HH - 2 - hs : hs);
    };

    int hrn = hrOf(0);
    float4 vnext = *(const float4*)&plane[hrn * WW + 4 * l];
    float ghnext = rowsum[b * HH + hrn];
    float4 xprev = make_float4(0.f, 0.f, 0.f, 0.f);

    for (int j = 0; j <= 17; ++j) {
        float4 v;
        if (j <= 16) {
            v = vnext;
            const float gh = ghnext * (1.f / WW);
            if (j < 16) {                         // prefetch next row + rowsum
                hrn = hrOf(j + 1);
                vnext = *(const float4*)&plane[hrn * WW + 4 * l];
                ghnext = rowsum[b * HH + hrn];
            }

            // horizontal neighbors via shuffles; reflect edges from own regs
            float xm2 = __shfl_up(v.z, 1);
            float xm1 = __shfl_up(v.w, 1);
            float xp4 = __shfl_down(v.x, 1);
            float xp5 = __shfl_down(v.y, 1);
            if (l == 0)  { xm2 = v.z; xm1 = v.y; }   // x[-2]=x[2], x[-1]=x[1]
            if (l == 63) { xp4 = v.z; xp5 = v.y; }   // x[256]=x[254], x[257]=x[253]

            const float h0v = fh[0] * xm2 + fh[1] * xm1 + fh[2] * v.x + fh[3] * v.y + fh[4] * v.z;
            const float h1v = fh[0] * xm1 + fh[1] * v.x + fh[2] * v.y + fh[3] * v.z + fh[4] * v.w;
            const float h2v = fh[0] * v.x + fh[1] * v.y + fh[2] * v.z + fh[3] * v.w + fh[4] * xp4;
            const float h3v = fh[0] * v.y + fh[1] * v.z + fh[2] * v.w + fh[3] * xp4 + fh[4] * xp5;

            float4 r1;
            r1.x = Ah * h0v - Bh * gh + Ch * v.x;
            r1.y = Ah * h1v - Bh * gh + Ch * v.y;
            r1.z = Ah * h2v - Bh * gh + Ch * v.z;
            r1.w = Ah * h3v - Bh * gh + Ch * v.w;

            const int hs = h0 - 4 + 4 * j + wv;
            *(float4*)&hring[hs & 15][4 * l] = r1;
        }
        __syncthreads();

        if (j >= 2) {
            const int O = h0 - 8 + 4 * j + wv;     // output row (= load row of j-1)
            float ax = 0.f, ay = 0.f, az = 0.f, aw = 0.f;
            float4 rc;
#pragma unroll
            for (int k = 0; k < 5; ++k) {
                int vrow = O + k - 2;
                int vr = vrow < 0 ? -vrow : (vrow > HH - 1 ? 2 * HH - 2 - vrow : vrow);
                float4 hv = *(const float4*)&hring[vr & 15][4 * l];
                ax += fv[k] * hv.x;
                ay += fv[k] * hv.y;
                az += fv[k] * hv.z;
                aw += fv[k] * hv.w;
                if (k == 2) rc = hv;
            }
            float4 res;
            res.x = gm * (Av * ax - Bv * gx[0] + Cv * rc.x) + bt * xprev.x;
            res.y = gm * (Av * ay - Bv * gx[1] + Cv * rc.y) + bt * xprev.y;
            res.z = gm * (Av * az - Bv * gx[2] + Cv * rc.z) + bt * xprev.z;
            res.w = gm * (Av * aw - Bv * gx[3] + Cv * rc.w) + bt * xprev.w;
            *(float4*)&oplane[O * WW + 4 * l] = res;
        }

        if (j <= 16) xprev = v;
    }
}

// ---------------------------------------------------------------------------
extern "C" void kernel_launch(void* const* d_in, const int* in_sizes, int n_in,
                              void* d_out, int out_size, void* d_ws, size_t ws_size,
                              hipStream_t stream) {
    const float* x        = (const float*)d_in[0];
    const float* conv_h   = (const float*)d_in[1];
    const float* inside_h = (const float*)d_in[2];
    const float* lamb_l_h = (const float*)d_in[3];
    const float* lamb_h_h = (const float*)d_in[4];
    const float* conv_v   = (const float*)d_in[5];
    const float* inside_v = (const float*)d_in[6];
    const float* lamb_l_v = (const float*)d_in[7];
    const float* lamb_h_v = (const float*)d_in[8];
    const float* gamma    = (const float*)d_in[9];
    const float* beta     = (const float*)d_in[10];
    float* out = (float*)d_out;

    float* ws = (float*)d_ws;
    float* rowsum        = ws;            // NC*HH            = 131072
    float* colsum_part   = ws + 131072;   // NC*4*WW          = 524288
    float* planesum_part = ws + 655360;   // NC*4             = 2048
    float* planesum      = ws + 657408;   // NC               = 512
    float* f_h           = ws + 657920;   // 80
    float* f_v           = ws + 658000;   // 80

    k_reduce<<<NC * 4, 256, 0, stream>>>((const float4*)x, rowsum, colsum_part,
                                         planesum_part);
    k_small<<<1, 256, 0, stream>>>(colsum_part, planesum_part, conv_h, inside_h,
                                   lamb_l_h, lamb_h_h, conv_v, planesum, f_h, f_v);
    k_main<<<NC * 4, 256, 0, stream>>>(x, rowsum, colsum_part, planesum, f_h, f_v,
                                       inside_h, lamb_l_h, lamb_h_h,
                                       inside_v, lamb_l_v, lamb_h_v,
                                       gamma, beta, out);
}

// Round 4
// 82.944 us; speedup vs baseline: 1.0309x; 1.0309x over previous
//
#include <hip/hip_runtime.h>
#include <math.h>

// Problem constants (from reference): N=4, C=128, H=W=256, G=4, K=5, DIL=1
#define NB   4
#define CC   128
#define HH   256
#define WW   256
#define HWSZ (HH * WW)          // 65536
#define NC   (NB * CC)          // 512
#define GK   20                 // G*K

__device__ __forceinline__ float wave_reduce_sum(float v) {
#pragma unroll
    for (int o = 1; o < 64; o <<= 1) v += __shfl_xor(v, o, 64);
    return v;
}

// ---------------------------------------------------------------------------
// Kernel 1: partial plane reductions. 4 blocks per (n,c) plane, 64 rows each.
// Pure float4 accumulate (NO per-row shuffle chains). Produces partial
// colsum [b][chunk][w] and partial planesum [b*4+chunk]. Deterministic.
// ---------------------------------------------------------------------------
__global__ __launch_bounds__(256) void k_reduce(const float4* __restrict__ x4,
                                                float* __restrict__ colsum_part,
                                                float* __restrict__ planesum_part) {
    const int bx = blockIdx.x;
    const int b = bx >> 2;               // (n,c) index
    const int chunk = bx & 3;            // row chunk 0..3
    const int t = threadIdx.x;
    const int wv = t >> 6;               // wave id 0..3
    const int l = t & 63;                // lane
    const float4* plane = x4 + (size_t)b * (HWSZ / 4);
    const int r0 = chunk * 64 + wv * 16; // this wave's 16 rows

    float4 cs = make_float4(0.f, 0.f, 0.f, 0.f);
#pragma unroll 4
    for (int i = 0; i < 16; ++i) {
        float4 v = plane[(r0 + i) * (WW / 4) + l];
        cs.x += v.x; cs.y += v.y; cs.z += v.z; cs.w += v.w;
    }

    __shared__ float colpart[4][WW];
    colpart[wv][4 * l + 0] = cs.x;
    colpart[wv][4 * l + 1] = cs.y;
    colpart[wv][4 * l + 2] = cs.z;
    colpart[wv][4 * l + 3] = cs.w;
    __syncthreads();
    float c = (colpart[0][t] + colpart[1][t]) + (colpart[2][t] + colpart[3][t]);
    colsum_part[(size_t)b * 4 * WW + chunk * WW + t] = c;

    float p = wave_reduce_sum(c);
    __shared__ float pr[4];
    if (l == 0) pr[wv] = p;
    __syncthreads();
    if (t == 0) planesum_part[b * 4 + chunk] = (pr[0] + pr[1]) + (pr[2] + pr[3]);
}

// ---------------------------------------------------------------------------
// Kernel 2: fused main pass (f_h/f_v computed in prologue from partials;
// all L2-resident, redundantly per block — removes the tiny middle kernel).
//
// Reflect-pad boundary corrections for the horizontal conv plane-mean:
//   k=0 (shift -2): S + c1 + c2 - c254 - c255
//   k=1 (shift -1): S + c1 - c255
//   k=2 (shift  0): S
//   k=3 (shift +1): S + c254 - c0
//   k=4 (shift +2): S + c253 + c254 - c0 - c1
//
// Main loop: wave = one row (64 lanes x float4). Block = 4 rows/iteration.
// Horizontal 5-tap in registers via shuffles (reflect edges = own regs).
// Row mean on the fly via wave reduce. hconv rows -> 16-row LDS ring;
// vertical 5-tap reads 5x ds_read_b128. Output lags load by 1 iteration.
// ---------------------------------------------------------------------------
#define TH 64  // rows per block tile

__global__ __launch_bounds__(256) void k_main(const float* __restrict__ x,
                                              const float* __restrict__ colsum_part,
                                              const float* __restrict__ planesum_part,
                                              const float* __restrict__ conv_h,
                                              const float* __restrict__ conv_v,
                                              const float* __restrict__ inside_h,
                                              const float* __restrict__ lamb_l_h,
                                              const float* __restrict__ lamb_h_h,
                                              const float* __restrict__ inside_v,
                                              const float* __restrict__ lamb_l_v,
                                              const float* __restrict__ lamb_h_v,
                                              const float* __restrict__ gamma,
                                              const float* __restrict__ beta,
                                              float* __restrict__ out) {
    const int b = blockIdx.x >> 2;        // (n,c)
    const int tile = blockIdx.x & 3;
    const int h0 = tile * TH;
    const int n = b >> 7, c = b & (CC - 1), g = c >> 5;
    const int t = threadIdx.x;
    const int wv = t >> 6;                // wave id 0..3
    const int l = t & 63;                 // lane

    // ---- prologue: recompute filters from partials (L2-resident) ----
    __shared__ float meanx_s[CC];
    __shared__ float psum_s[CC];
    __shared__ float fh_all[GK];
    __shared__ float mo1_s[CC];
    __shared__ float fv_s[5];

    const float* pp = planesum_part + n * CC * 4;
    if (t < CC) {
        float S = (pp[t * 4 + 0] + pp[t * 4 + 1]) + (pp[t * 4 + 2] + pp[t * 4 + 3]);
        psum_s[t] = S;
        meanx_s[t] = S * (1.f / HWSZ);
    }
    __syncthreads();

    if (t < GK) {
        const float4* w4 = (const float4*)(conv_h + t * CC);
        float acc = 0.f;
#pragma unroll 8
        for (int i = 0; i < CC / 4; ++i) {
            float4 w = w4[i];
            acc += w.x * meanx_s[4 * i] + w.y * meanx_s[4 * i + 1] +
                   w.z * meanx_s[4 * i + 2] + w.w * meanx_s[4 * i + 3];
        }
        fh_all[t] = tanhf(acc);
    }
    __syncthreads();

    if (t < CC) {
        const float* f = &fh_all[(t >> 5) * 5];
        const float S = psum_s[t];
        const float* col = colsum_part + (size_t)(n * CC + t) * 4 * WW;
        auto csum = [&](int w) {
            return (col[0 * WW + w] + col[1 * WW + w]) +
                   (col[2 * WW + w] + col[3 * WW + w]);
        };
        const float c0 = csum(0), c1 = csum(1), c2 = csum(2);
        const float c253 = csum(253), c254 = csum(254), c255 = csum(255);
        const float s0 = S + c1 + c2 - c254 - c255;
        const float s1 = S + c1 - c255;
        const float s3 = S + c254 - c0;
        const float s4 = S + c253 + c254 - c0 - c1;
        const float convmean =
            (f[0] * s0 + f[1] * s1 + f[2] * S + f[3] * s3 + f[4] * s4) * (1.f / HWSZ);
        const float A = (inside_h[t] + 1.f) * lamb_l_h[t];
        const float B = inside_h[t] * lamb_l_h[t];
        const float Cq = lamb_h_h[t] + 1.f;
        mo1_s[t] = A * convmean + (Cq - B) * meanx_s[t];
    }
    __syncthreads();

    if (t < 5) {
        const float4* w4 = (const float4*)(conv_v + (g * 5 + t) * CC);
        float acc = 0.f;
#pragma unroll 8
        for (int i = 0; i < CC / 4; ++i) {
            float4 w = w4[i];
            acc += w.x * mo1_s[4 * i] + w.y * mo1_s[4 * i + 1] +
                   w.z * mo1_s[4 * i + 2] + w.w * mo1_s[4 * i + 3];
        }
        fv_s[t] = tanhf(acc);
    }

    // gapx_v column means into LDS (reflect pad)
    __shared__ float lcol[WW + 4];
    {
        const float* col = colsum_part + (size_t)b * 4 * WW;
        auto csum = [&](int w) {
            return ((col[0 * WW + w] + col[1 * WW + w]) +
                    (col[2 * WW + w] + col[3 * WW + w])) * (1.f / HH);
        };
        lcol[t + 2] = csum(t);
        if (t < 2) lcol[t] = csum(2 - t);
        if (t >= WW - 2) lcol[t + 4] = csum(2 * WW - 4 - t);
    }
    __syncthreads();

    float fh[5], fv[5];
#pragma unroll
    for (int k = 0; k < 5; ++k) {
        fh[k] = fh_all[g * 5 + k];
        fv[k] = fv_s[k];
    }
    const float Ah = (inside_h[c] + 1.f) * lamb_l_h[c];
    const float Bh = inside_h[c] * lamb_l_h[c];
    const float Ch = lamb_h_h[c] + 1.f;
    const float Av = (inside_v[c] + 1.f) * lamb_l_v[c];
    const float Bv = inside_v[c] * lamb_l_v[c];
    const float Cv = lamb_h_v[c] + 1.f;
    const float gm = gamma[c], bt = beta[c];
    const float meanx = meanx_s[c];

    float gx[4];
    {
        float q[8];
#pragma unroll
        for (int d = 0; d < 8; ++d) q[d] = lcol[4 * l + d];
#pragma unroll
        for (int d = 0; d < 4; ++d) {
            gx[d] = Ah * (fh[0] * q[d] + fh[1] * q[d + 1] + fh[2] * q[d + 2] +
                          fh[3] * q[d + 3] + fh[4] * q[d + 4]) -
                    Bh * meanx + Ch * q[d + 2];
        }
    }

    __shared__ float hring[16][WW];       // hconv ring (16 rows)
    const float* plane = x + (size_t)b * HWSZ;
    float* oplane = out + (size_t)b * HWSZ;

    // load row for super-iter j (wave wv): hs = h0 - 4 + 4j + wv
    auto rowptr = [&](int j) -> const float4* {
        int hs = h0 - 4 + 4 * j + wv;
        int hr = hs < 0 ? -hs : (hs > HH - 1 ? 2 * HH - 2 - hs : hs);
        return (const float4*)&plane[hr * WW + 4 * l];
    };

    float4 vnext = *rowptr(0);
    float4 xprev = make_float4(0.f, 0.f, 0.f, 0.f);

    for (int j = 0; j <= 17; ++j) {
        float4 v;
        if (j <= 16) {
            v = vnext;
            if (j < 16) vnext = *rowptr(j + 1);   // prefetch next row

            // row mean on the fly
            float rsum = (v.x + v.y) + (v.z + v.w);
            rsum = wave_reduce_sum(rsum);
            const float gh = rsum * (1.f / WW);

            // horizontal neighbors via shuffles; reflect edges from own regs
            float xm2 = __shfl_up(v.z, 1);
            float xm1 = __shfl_up(v.w, 1);
            float xp4 = __shfl_down(v.x, 1);
            float xp5 = __shfl_down(v.y, 1);
            if (l == 0)  { xm2 = v.z; xm1 = v.y; }   // x[-2]=x[2], x[-1]=x[1]
            if (l == 63) { xp4 = v.z; xp5 = v.y; }   // x[256]=x[254], x[257]=x[253]

            const float h0v = fh[0] * xm2 + fh[1] * xm1 + fh[2] * v.x + fh[3] * v.y + fh[4] * v.z;
            const float h1v = fh[0] * xm1 + fh[1] * v.x + fh[2] * v.y + fh[3] * v.z + fh[4] * v.w;
            const float h2v = fh[0] * v.x + fh[1] * v.y + fh[2] * v.z + fh[3] * v.w + fh[4] * xp4;
            const float h3v = fh[0] * v.y + fh[1] * v.z + fh[2] * v.w + fh[3] * xp4 + fh[4] * xp5;

            float4 r1;
            r1.x = Ah * h0v - Bh * gh + Ch * v.x;
            r1.y = Ah * h1v - Bh * gh + Ch * v.y;
            r1.z = Ah * h2v - Bh * gh + Ch * v.z;
            r1.w = Ah * h3v - Bh * gh + Ch * v.w;

            const int hs = h0 - 4 + 4 * j + wv;
            *(float4*)&hring[hs & 15][4 * l] = r1;
        }
        __syncthreads();

        if (j >= 2) {
            const int O = h0 - 8 + 4 * j + wv;     // output row (= load row of j-1)
            float ax = 0.f, ay = 0.f, az = 0.f, aw = 0.f;
            float4 rc;
#pragma unroll
            for (int k = 0; k < 5; ++k) {
                int vrow = O + k - 2;
                int vr = vrow < 0 ? -vrow : (vrow > HH - 1 ? 2 * HH - 2 - vrow : vrow);
                float4 hv = *(const float4*)&hring[vr & 15][4 * l];
                ax += fv[k] * hv.x;
                ay += fv[k] * hv.y;
                az += fv[k] * hv.z;
                aw += fv[k] * hv.w;
                if (k == 2) rc = hv;
            }
            float4 res;
            res.x = gm * (Av * ax - Bv * gx[0] + Cv * rc.x) + bt * xprev.x;
            res.y = gm * (Av * ay - Bv * gx[1] + Cv * rc.y) + bt * xprev.y;
            res.z = gm * (Av * az - Bv * gx[2] + Cv * rc.z) + bt * xprev.z;
            res.w = gm * (Av * aw - Bv * gx[3] + Cv * rc.w) + bt * xprev.w;
            *(float4*)&oplane[O * WW + 4 * l] = res;
        }

        if (j <= 16) xprev = v;
    }
}

// ---------------------------------------------------------------------------
extern "C" void kernel_launch(void* const* d_in, const int* in_sizes, int n_in,
                              void* d_out, int out_size, void* d_ws, size_t ws_size,
                              hipStream_t stream) {
    const float* x        = (const float*)d_in[0];
    const float* conv_h   = (const float*)d_in[1];
    const float* inside_h = (const float*)d_in[2];
    const float* lamb_l_h = (const float*)d_in[3];
    const float* lamb_h_h = (const float*)d_in[4];
    const float* conv_v   = (const float*)d_in[5];
    const float* inside_v = (const float*)d_in[6];
    const float* lamb_l_v = (const float*)d_in[7];
    const float* lamb_h_v = (const float*)d_in[8];
    const float* gamma    = (const float*)d_in[9];
    const float* beta     = (const float*)d_in[10];
    float* out = (float*)d_out;

    float* ws = (float*)d_ws;
    float* colsum_part   = ws;            // NC*4*WW = 524288
    float* planesum_part = ws + 524288;   // NC*4    = 2048

    k_reduce<<<NC * 4, 256, 0, stream>>>((const float4*)x, colsum_part,
                                         planesum_part);
    k_main<<<NC * 4, 256, 0, stream>>>(x, colsum_part, planesum_part,
                                       conv_h, conv_v,
                                       inside_h, lamb_l_h, lamb_h_h,
                                       inside_v, lamb_l_v, lamb_h_v,
                                       gamma, beta, out);
}